// Round 1
// baseline (1206.716 us; speedup 1.0000x reference)
//
#include <hip/hip_runtime.h>
#include <hip/hip_bf16.h>

// Problem constants
#define B_DIM 256
#define C_DIM 4096
#define FIN   160
#define FHID  192
#define EPS   1e-5f

typedef short  short8  __attribute__((ext_vector_type(8)));
typedef float  floatx4 __attribute__((ext_vector_type(4)));

__device__ __forceinline__ short f2bs(float f) {
  __hip_bfloat16 h = __float2bfloat16(f);   // RNE
  return *reinterpret_cast<short*>(&h);
}

__device__ __forceinline__ void cvt_store8(short* dst, const float4& v0, const float4& v1) {
  short8 s;
  s[0] = f2bs(v0.x); s[1] = f2bs(v0.y); s[2] = f2bs(v0.z); s[3] = f2bs(v0.w);
  s[4] = f2bs(v1.x); s[5] = f2bs(v1.y); s[6] = f2bs(v1.z); s[7] = f2bs(v1.w);
  *reinterpret_cast<short8*>(dst) = s;      // 16B aligned store
}

// ================= big-LDS kernel: whole-tile single-burst staging ==========
// LDS row stride 168 shorts = 336 B = 21 x 16B granules. b128 reads at byte
// r*336 + 16*g start at bank-group (84*r + 4*g) mod 32; 84 mod 32 = 20 cycles
// through 8 distinct 4-bank groups over consecutive rows -> uniform
// 8 accesses/bank = wave64-b128 wire minimum (no conflicts).
#define AST_BIG 168
#define A_SH (B_DIM * AST_BIG)                 // 43008 shorts = 86016 B
#define B_SH (FHID  * AST_BIG)                 // 32256 shorts = 64512 B
// epilogue arrays: psum[4][192] + psq[4][192] + scale/shift/w2[192] + rowp[4][256]
#define SMEM_BYTES (A_SH*2 + B_SH*2 + (8*FHID + 3*FHID + 4*B_DIM)*4)   // 163072 <= 163840

__global__ __launch_bounds__(1024) void mlp_fused_big(
    const float* __restrict__ x,     // [B, C, FIN]
    const float* __restrict__ W1,    // [C, FHID, FIN]
    const float* __restrict__ gamma, // [C, FHID]
    const float* __restrict__ beta,  // [C, FHID]
    const float* __restrict__ W2,    // [C, 1, FHID]
    const float* __restrict__ b2,    // [C, 1]
    float* __restrict__ out)         // [B, C, 1]
{
  extern __shared__ __align__(16) char smem[];
  short* Alds   = reinterpret_cast<short*>(smem);
  short* Blds   = Alds + A_SH;
  float* psum   = reinterpret_cast<float*>(smem + (size_t)(A_SH + B_SH) * 2); // [4][FHID]
  float* psq    = psum + 4 * FHID;                                            // [4][FHID]
  float* scaleS = psq + 4 * FHID;
  float* shiftS = scaleS + FHID;
  float* w2S    = shiftS + FHID;
  float* rowp   = w2S + FHID;                                                 // [4][B_DIM]

  const int c    = blockIdx.x;
  const int tid  = threadIdx.x;
  const int lane = tid & 63;
  const int wave = tid >> 6;     // 0..15
  const int wr   = wave >> 2;    // 0..3
  const int wc   = wave & 3;     // 0..3
  const int l15  = lane & 15;
  const int lg   = lane >> 4;    // 0..3

  const float* xc  = x  + (size_t)c * FIN;
  const float* w1c = W1 + (size_t)c * FHID * FIN;

  // ---- mega-stage: entire A (256x160) and B (192x160) tiles, bf16 ----
  // 4 threads per row; per round j each 4-thread group reads 128 contiguous B,
  // 5 back-to-back rounds stream the full 640-B row in one burst.
  const int  r    = tid >> 2;            // A row 0..255 (B row 0..191 for tid<768)
  const int  q    = tid & 3;
  const bool bact = tid < 4 * FHID;      // 768 threads = waves 0..11 (wave-uniform)

  {
    const float* pa = xc + (size_t)r * (C_DIM * FIN) + q * 8;
    const float* pb = w1c + r * FIN + q * 8;

    float4 av[10];
    float4 bv[10];
    #pragma unroll
    for (int j = 0; j < 5; ++j) {
      av[2*j]   = *reinterpret_cast<const float4*>(pa + j*32);
      av[2*j+1] = *reinterpret_cast<const float4*>(pa + j*32 + 4);
    }
    if (bact) {
      #pragma unroll
      for (int j = 0; j < 5; ++j) {
        bv[2*j]   = *reinterpret_cast<const float4*>(pb + j*32);
        bv[2*j+1] = *reinterpret_cast<const float4*>(pb + j*32 + 4);
      }
    }
    short* da = Alds + r * AST_BIG + q * 8;
    #pragma unroll
    for (int j = 0; j < 5; ++j) cvt_store8(da + j*32, av[2*j], av[2*j+1]);
    if (bact) {
      short* db = Blds + r * AST_BIG + q * 8;
      #pragma unroll
      for (int j = 0; j < 5; ++j) cvt_store8(db + j*32, bv[2*j], bv[2*j+1]);
    }
  }
  __syncthreads();   // the ONLY barrier before the epilogue

  // ---- GEMM1: 5 K-chunks from LDS, no barriers, no global traffic ----
  floatx4 acc[4][3];
  #pragma unroll
  for (int mt = 0; mt < 4; ++mt)
    #pragma unroll
    for (int nt = 0; nt < 3; ++nt)
      acc[mt][nt] = (floatx4)(0.f);

  // ds_read bases: compile-time immediate offsets for mt/nt/kc
  const short* aB = Alds + (wr * 64 + l15) * AST_BIG + lg * 8;
  const short* bB = Blds + (wc * 48 + l15) * AST_BIG + lg * 8;

  #pragma unroll
  for (int kc = 0; kc < 5; ++kc) {
    short8 af[4], bf[3];
    #pragma unroll
    for (int mt = 0; mt < 4; ++mt)
      af[mt] = *reinterpret_cast<const short8*>(aB + mt * 16 * AST_BIG + kc * 32);
    #pragma unroll
    for (int nt = 0; nt < 3; ++nt)
      bf[nt] = *reinterpret_cast<const short8*>(bB + nt * 16 * AST_BIG + kc * 32);
    #pragma unroll
    for (int mt = 0; mt < 4; ++mt)
      #pragma unroll
      for (int nt = 0; nt < 3; ++nt)
        acc[mt][nt] = __builtin_amdgcn_mfma_f32_16x16x32_bf16(
            af[mt], bf[nt], acc[mt][nt], 0, 0, 0);
  }

  // ---- BatchNorm stats: mean/var over batch per (c, col) ----
  // C/D layout: col = lane&15, row_in_tile = lg*4 + reg   (m89-verified)
  #pragma unroll
  for (int nt = 0; nt < 3; ++nt) {
    float s = 0.f, qq = 0.f;
    #pragma unroll
    for (int mt = 0; mt < 4; ++mt)
      #pragma unroll
      for (int rr = 0; rr < 4; ++rr) {
        const float v = acc[mt][nt][rr];
        s += v; qq += v * v;
      }
    s += __shfl_xor(s, 16); qq += __shfl_xor(qq, 16);
    s += __shfl_xor(s, 32); qq += __shfl_xor(qq, 32);
    if (lg == 0) {
      const int col = wc * 48 + nt * 16 + l15;
      psum[wr * FHID + col] = s;
      psq [wr * FHID + col] = qq;
    }
  }
  __syncthreads();

  if (tid < FHID) {
    const float s  = psum[0*FHID + tid] + psum[1*FHID + tid] + psum[2*FHID + tid] + psum[3*FHID + tid];
    const float qq = psq [0*FHID + tid] + psq [1*FHID + tid] + psq [2*FHID + tid] + psq [3*FHID + tid];
    const float mean = s * (1.f / 256.f);
    const float var  = qq * (1.f / 256.f) - mean * mean;   // biased
    const float rstd = rsqrtf(var + EPS);
    const float sc   = rstd * gamma[(size_t)c * FHID + tid];
    scaleS[tid] = sc;
    shiftS[tid] = beta[(size_t)c * FHID + tid] - mean * sc;
    w2S[tid]    = W2[(size_t)c * FHID + tid];
  }
  __syncthreads();

  // ---- normalize + ReLU + dot(W2) epilogue ----
  #pragma unroll
  for (int mt = 0; mt < 4; ++mt) {
    #pragma unroll
    for (int rr = 0; rr < 4; ++rr) {
      float p = 0.f;
      #pragma unroll
      for (int nt = 0; nt < 3; ++nt) {
        const int col = wc * 48 + nt * 16 + l15;
        float v = acc[mt][nt][rr] * scaleS[col] + shiftS[col];
        v = fmaxf(v, 0.f);
        p += v * w2S[col];
      }
      p += __shfl_xor(p, 1);
      p += __shfl_xor(p, 2);
      p += __shfl_xor(p, 4);
      p += __shfl_xor(p, 8);
      if (l15 == 0) {
        const int row = wr * 64 + mt * 16 + lg * 4 + rr;
        rowp[wc * B_DIM + row] = p;
      }
    }
  }
  __syncthreads();

  if (tid < B_DIM) {
    const float o = rowp[0*B_DIM + tid] + rowp[1*B_DIM + tid]
                  + rowp[2*B_DIM + tid] + rowp[3*B_DIM + tid] + b2[c];
    out[(size_t)tid * C_DIM + c] = o;
  }
}

// ================= fallback: previous known-good kernel (static 48KB LDS) ===
#define AST 40
#define BST 40

__global__ __launch_bounds__(1024) void mlp_fused_small(
    const float* __restrict__ x,
    const float* __restrict__ W1,
    const float* __restrict__ gamma,
    const float* __restrict__ beta,
    const float* __restrict__ W2,
    const float* __restrict__ b2,
    float* __restrict__ out)
{
  const int c    = blockIdx.x;
  const int tid  = threadIdx.x;
  const int lane = tid & 63;
  const int wave = tid >> 6;
  const int wr   = wave >> 2;
  const int wc   = wave & 3;
  const int l15  = lane & 15;
  const int lg   = lane >> 4;

  __shared__ __align__(16) short Alds[B_DIM * AST];
  __shared__ __align__(16) short Blds[FHID * BST];
  __shared__ float psum[4][FHID];
  __shared__ float psq [4][FHID];
  __shared__ float scaleS[FHID];
  __shared__ float shiftS[FHID];
  __shared__ float w2S[FHID];
  __shared__ float rowp[4][B_DIM];

  const float* xc  = x  + (size_t)c * FIN;
  const float* w1c = W1 + (size_t)c * FHID * FIN;

  const int  arow = tid >> 2;
  const int  aq   = (tid & 3) * 8;
  const bool bact = tid < 768;

  float4 a0, a1, b0, b1;
  {
    const float* pa = xc + (size_t)arow * (C_DIM * FIN) + aq;
    a0 = *reinterpret_cast<const float4*>(pa);
    a1 = *reinterpret_cast<const float4*>(pa + 4);
    if (bact) {
      const float* pb = w1c + arow * FIN + aq;
      b0 = *reinterpret_cast<const float4*>(pb);
      b1 = *reinterpret_cast<const float4*>(pb + 4);
    }
  }

  floatx4 acc[4][3];
  #pragma unroll
  for (int mt = 0; mt < 4; ++mt)
    #pragma unroll
    for (int nt = 0; nt < 3; ++nt)
      acc[mt][nt] = (floatx4)(0.f);

  for (int kc = 0; kc < 5; ++kc) {
    cvt_store8(&Alds[arow * AST + aq], a0, a1);
    if (bact) cvt_store8(&Blds[arow * BST + aq], b0, b1);
    __syncthreads();

    if (kc < 4) {
      const int k0 = (kc + 1) * 32;
      const float* pa = xc + (size_t)arow * (C_DIM * FIN) + k0 + aq;
      a0 = *reinterpret_cast<const float4*>(pa);
      a1 = *reinterpret_cast<const float4*>(pa + 4);
      if (bact) {
        const float* pb = w1c + arow * FIN + k0 + aq;
        b0 = *reinterpret_cast<const float4*>(pb);
        b1 = *reinterpret_cast<const float4*>(pb + 4);
      }
    }

    short8 af[4], bf[3];
    #pragma unroll
    for (int mt = 0; mt < 4; ++mt) {
      const int row = wr * 64 + mt * 16 + l15;
      af[mt] = *reinterpret_cast<const short8*>(&Alds[row * AST + lg * 8]);
    }
    #pragma unroll
    for (int nt = 0; nt < 3; ++nt) {
      const int row = wc * 48 + nt * 16 + l15;
      bf[nt] = *reinterpret_cast<const short8*>(&Blds[row * BST + lg * 8]);
    }
    #pragma unroll
    for (int mt = 0; mt < 4; ++mt)
      #pragma unroll
      for (int nt = 0; nt < 3; ++nt)
        acc[mt][nt] = __builtin_amdgcn_mfma_f32_16x16x32_bf16(
            af[mt], bf[nt], acc[mt][nt], 0, 0, 0);
    __syncthreads();
  }

  #pragma unroll
  for (int nt = 0; nt < 3; ++nt) {
    float s = 0.f, qv = 0.f;
    #pragma unroll
    for (int mt = 0; mt < 4; ++mt)
      #pragma unroll
      for (int rr = 0; rr < 4; ++rr) {
        const float v = acc[mt][nt][rr];
        s += v; qv += v * v;
      }
    s += __shfl_xor(s, 16); qv += __shfl_xor(qv, 16);
    s += __shfl_xor(s, 32); qv += __shfl_xor(qv, 32);
    if (lg == 0) {
      const int col = wc * 48 + nt * 16 + l15;
      psum[wr][col] = s;
      psq [wr][col] = qv;
    }
  }
  __syncthreads();

  if (tid < FHID) {
    const float s  = psum[0][tid] + psum[1][tid] + psum[2][tid] + psum[3][tid];
    const float qv = psq [0][tid] + psq [1][tid] + psq [2][tid] + psq [3][tid];
    const float mean = s * (1.f / 256.f);
    const float var  = qv * (1.f / 256.f) - mean * mean;
    const float rstd = rsqrtf(var + EPS);
    const float sc   = rstd * gamma[(size_t)c * FHID + tid];
    scaleS[tid] = sc;
    shiftS[tid] = beta[(size_t)c * FHID + tid] - mean * sc;
    w2S[tid]    = W2[(size_t)c * FHID + tid];
  }
  __syncthreads();

  #pragma unroll
  for (int mt = 0; mt < 4; ++mt) {
    #pragma unroll
    for (int rr = 0; rr < 4; ++rr) {
      float p = 0.f;
      #pragma unroll
      for (int nt = 0; nt < 3; ++nt) {
        const int col = wc * 48 + nt * 16 + l15;
        float v = acc[mt][nt][rr] * scaleS[col] + shiftS[col];
        v = fmaxf(v, 0.f);
        p += v * w2S[col];
      }
      p += __shfl_xor(p, 1);
      p += __shfl_xor(p, 2);
      p += __shfl_xor(p, 4);
      p += __shfl_xor(p, 8);
      if (l15 == 0) {
        const int row = wr * 64 + mt * 16 + lg * 4 + rr;
        rowp[wc][row] = p;
      }
    }
  }
  __syncthreads();

  if (tid < B_DIM) {
    const float o = rowp[0][tid] + rowp[1][tid] + rowp[2][tid] + rowp[3][tid] + b2[c];
    out[(size_t)tid * C_DIM + c] = o;
  }
}

extern "C" void kernel_launch(void* const* d_in, const int* in_sizes, int n_in,
                              void* d_out, int out_size, void* d_ws, size_t ws_size,
                              hipStream_t stream) {
  const float* x     = (const float*)d_in[0];
  const float* W1    = (const float*)d_in[1];
  const float* gamma = (const float*)d_in[2];
  const float* beta  = (const float*)d_in[3];
  const float* W2    = (const float*)d_in[4];
  const float* b2    = (const float*)d_in[5];
  float* out = (float*)d_out;

  // >64KB dynamic LDS needs the opt-in attribute; fall back to the known-good
  // kernel if the attribute or the launch is rejected (guarantees pass).
  static int use_big = -1;
  if (use_big < 0) {
    use_big = (hipFuncSetAttribute(reinterpret_cast<const void*>(mlp_fused_big),
                                   hipFuncAttributeMaxDynamicSharedMemorySize,
                                   SMEM_BYTES) == hipSuccess) ? 1 : 0;
  }
  if (use_big) {
    (void)hipGetLastError();  // clear stale errors
    mlp_fused_big<<<C_DIM, 1024, SMEM_BYTES, stream>>>(x, W1, gamma, beta, W2, b2, out);
    if (hipGetLastError() != hipSuccess) use_big = 0;   // launch rejected -> fallback
  }
  if (!use_big) {
    mlp_fused_small<<<C_DIM, 1024, 0, stream>>>(x, W1, gamma, beta, W2, b2, out);
  }
}